// Round 1
// baseline (1237.995 us; speedup 1.0000x reference)
//
#include <hip/hip_runtime.h>

#define N_ENT 200000
#define N_USR 100000
#define DIM 64
#define NE 1500000
#define NI_ 1000000
#define NREL1 10     // N_REL - 1
#define NVIRT 3
#define EPSF 1e-12f
#define SCAN_B 1024

// ---------- float4 helpers (avoid operator conflicts with HIP headers) ----------
__device__ __forceinline__ float4 f4_zero() { return make_float4(0.f, 0.f, 0.f, 0.f); }
__device__ __forceinline__ float4 f4_add(float4 a, float4 b) {
    return make_float4(a.x + b.x, a.y + b.y, a.z + b.z, a.w + b.w);
}
__device__ __forceinline__ float4 f4_scale(float s, float4 a) {
    return make_float4(s * a.x, s * a.y, s * a.z, s * a.w);
}
__device__ __forceinline__ float4 f4_fma(float s, float4 a, float4 b) { // s*a + b
    return make_float4(fmaf(s, a.x, b.x), fmaf(s, a.y, b.y), fmaf(s, a.z, b.z), fmaf(s, a.w, b.w));
}
__device__ __forceinline__ float f4_dot(float4 a, float4 b) {
    return a.x * b.x + a.y * b.y + a.z * b.z + a.w * b.w;
}
// sum across the 16-lane subgroup (wave64 split into 4 aligned segments of 16)
__device__ __forceinline__ float red16(float v) {
    v += __shfl_xor(v, 1, 16);
    v += __shfl_xor(v, 2, 16);
    v += __shfl_xor(v, 4, 16);
    v += __shfl_xor(v, 8, 16);
    return v;
}
// squash: u *= ||u||^2 / ((||u||^2+1) * max(||u||, eps)) ; sq is full 64-dim ||u||^2
__device__ __forceinline__ float4 squash4(float4 u, float sq) {
    float n = sqrtf(sq);
    float s = sq / ((sq + 1.f) * fmaxf(n, EPSF));
    return f4_scale(s, u);
}

// ---------- tiny precompute kernels ----------
__global__ void k_remap(const float* __restrict__ rw, const float* __restrict__ lat,
                        int* __restrict__ remap) {
    int r = threadIdx.x;
    if (r < NREL1) {
        float best = -3.4e38f; int bi = 0;
        for (int j = 0; j < NVIRT; j++) {
            float s = 0.f;
            for (int d = 0; d < DIM; d++) s += rw[r * DIM + d] * lat[j * DIM + d];
            if (s > best) { best = s; bi = j; }   // strict > : first-max tie-break like argmax
        }
        remap[r] = bi;
    }
}

__global__ void k_soft(const float* __restrict__ aw, float* __restrict__ wsoft) {
    int h = threadIdx.x;
    if (h < 2) {
        float a0 = aw[h * 3 + 0], a1 = aw[h * 3 + 1], a2 = aw[h * 3 + 2];
        float m = fmaxf(a0, fmaxf(a1, a2));
        float e0 = expf(a0 - m), e1 = expf(a1 - m), e2 = expf(a2 - m);
        float s = e0 + e1 + e2;
        wsoft[h * 3 + 0] = e0 / s; wsoft[h * 3 + 1] = e1 / s; wsoft[h * 3 + 2] = e2 / s;
    }
}

// ---------- CSR build ----------
__global__ void k_count(const int* __restrict__ idx, int n, int* __restrict__ cnt) {
    int i = blockIdx.x * blockDim.x + threadIdx.x;
    if (i < n) atomicAdd(&cnt[idx[i]], 1);
}

__global__ void k_scan1(const int* __restrict__ in, int* __restrict__ excl,
                        int* __restrict__ bsum, int n) {
    __shared__ int s[SCAN_B];
    int tid = threadIdx.x, gid = blockIdx.x * SCAN_B + tid;
    int v = (gid < n) ? in[gid] : 0;
    s[tid] = v; __syncthreads();
    for (int off = 1; off < SCAN_B; off <<= 1) {
        int t = 0;
        if (tid >= off) t = s[tid - off];
        __syncthreads();
        s[tid] += t;
        __syncthreads();
    }
    if (gid < n) excl[gid] = s[tid] - v;
    if (tid == SCAN_B - 1) bsum[blockIdx.x] = s[tid];
}

__global__ void k_scan2(int* __restrict__ bsum, int nb) {
    __shared__ int s[SCAN_B];
    int tid = threadIdx.x;
    int v = (tid < nb) ? bsum[tid] : 0;
    s[tid] = v; __syncthreads();
    for (int off = 1; off < SCAN_B; off <<= 1) {
        int t = 0;
        if (tid >= off) t = s[tid - off];
        __syncthreads();
        s[tid] += t;
        __syncthreads();
    }
    if (tid < nb) bsum[tid] = s[tid] - v;  // exclusive
}

__global__ void k_scan3(const int* __restrict__ excl, const int* __restrict__ bsum,
                        const int* __restrict__ cnt, int* __restrict__ rp,
                        int* __restrict__ cur, int n) {
    int gid = blockIdx.x * SCAN_B + threadIdx.x;
    if (gid < n) {
        int v = excl[gid] + bsum[blockIdx.x];
        rp[gid] = v;
        cur[gid] = v;
        if (gid == n - 1) rp[n] = v + cnt[gid];
    }
}

__global__ void k_scatter_ent(const int* __restrict__ head, const int* __restrict__ tail,
                              const int* __restrict__ etype, const int* __restrict__ remap,
                              int* __restrict__ cur, int* __restrict__ sorted) {
    int e = blockIdx.x * blockDim.x + threadIdx.x;
    if (e < NE) {
        int h = head[e];
        int v = remap[etype[e] - 1];
        int pos = atomicAdd(&cur[h], 1);
        sorted[pos] = tail[e] | (v << 18);   // tail < 2^18
    }
}

__global__ void k_scatter_usr(const int* __restrict__ ui, const int* __restrict__ ii,
                              int* __restrict__ cur, int* __restrict__ sorted) {
    int e = blockIdx.x * blockDim.x + threadIdx.x;
    if (e < NI_) {
        int pos = atomicAdd(&cur[ui[e]], 1);
        sorted[pos] = ii[e];
    }
}

// ---------- fused per-hop entity LWS (3 virts, 3 iters, agg + l2norm + residual) ----------
__global__ __launch_bounds__(256) void k_entity(
    const float* __restrict__ ent, const int* __restrict__ rp, const int* __restrict__ sorted,
    const float* __restrict__ wsoft, int hop, float* __restrict__ ent_next, int do_store,
    float* __restrict__ out)
{
    int g = (blockIdx.x * blockDim.x + threadIdx.x) >> 4;
    int lane = threadIdx.x & 15;
    if (g >= N_ENT) return;
    int start = rp[g], end = rp[g + 1];
    const float4* entv = (const float4*)ent;
    float4 eh = entv[g * 16 + lane];

    float4 u1[NVIRT], u2[NVIRT], acc[NVIRT];
    float cnt[NVIRT] = {0.f, 0.f, 0.f};
    float inv[NVIRT];
    acc[0] = acc[1] = acc[2] = f4_zero();

    // ---- iter 0: u1_v = squash(sum_x / denom) + eh
    for (int e = start; e < end; e++) {
        int p = sorted[e];
        int t = p & 0x3FFFF;
        int v = p >> 18;
        float4 x = entv[t * 16 + lane];
        if (v == 0)      { acc[0] = f4_add(acc[0], x); cnt[0] += 1.f; }
        else if (v == 1) { acc[1] = f4_add(acc[1], x); cnt[1] += 1.f; }
        else             { acc[2] = f4_add(acc[2], x); cnt[2] += 1.f; }
    }
    #pragma unroll
    for (int v = 0; v < NVIRT; v++) {
        inv[v] = 1.f / fmaxf(cnt[v], 1.f);
        float4 u = f4_scale(inv[v], acc[v]);
        float sq = red16(f4_dot(u, u));
        u1[v] = f4_add(squash4(u, sq), eh);
        acc[v] = f4_zero();
    }

    // ---- iter 1: scale per edge = d1 = dot(u1_v, x); u2_v = squash(sum d1*x / denom) + eh
    for (int e = start; e < end; e++) {
        int p = sorted[e];
        int t = p & 0x3FFFF;
        int v = p >> 18;
        float4 x = entv[t * 16 + lane];
        float4 uv = (v == 0) ? u1[0] : ((v == 1) ? u1[1] : u1[2]);
        float d1 = red16(f4_dot(uv, x));
        if (v == 0)      acc[0] = f4_fma(d1, x, acc[0]);
        else if (v == 1) acc[1] = f4_fma(d1, x, acc[1]);
        else             acc[2] = f4_fma(d1, x, acc[2]);
    }
    #pragma unroll
    for (int v = 0; v < NVIRT; v++) {
        float4 u = f4_scale(inv[v], acc[v]);
        float sq = red16(f4_dot(u, u));
        u2[v] = f4_add(squash4(u, sq), eh);
        acc[v] = f4_zero();
    }

    // ---- iter 2: scale per edge = d1^2 * d2 (d1 recomputed from retained u1); no squash
    for (int e = start; e < end; e++) {
        int p = sorted[e];
        int t = p & 0x3FFFF;
        int v = p >> 18;
        float4 x = entv[t * 16 + lane];
        float4 uv1 = (v == 0) ? u1[0] : ((v == 1) ? u1[1] : u1[2]);
        float4 uv2 = (v == 0) ? u2[0] : ((v == 1) ? u2[1] : u2[2]);
        float pd1 = f4_dot(uv1, x);
        float pd2 = f4_dot(uv2, x);
        float d1 = red16(pd1);
        float d2 = red16(pd2);
        float s = d1 * d1 * d2;
        if (v == 0)      acc[0] = f4_fma(s, x, acc[0]);
        else if (v == 1) acc[1] = f4_fma(s, x, acc[1]);
        else             acc[2] = f4_fma(s, x, acc[2]);
    }
    float w0 = wsoft[hop * 3 + 0], w1 = wsoft[hop * 3 + 1], w2 = wsoft[hop * 3 + 2];
    float4 agg = f4_zero();
    #pragma unroll
    for (int v = 0; v < NVIRT; v++) {
        float4 u3 = f4_add(f4_scale(inv[v], acc[v]), eh);
        float w = (v == 0) ? w0 : ((v == 1) ? w1 : w2);
        agg = f4_fma(w, u3, agg);
    }
    // l2norm + residual
    float sq = red16(f4_dot(agg, agg));
    float n = sqrtf(sq);
    float4 en = f4_scale(1.f / fmaxf(n, EPSF), agg);
    if (do_store) {
        float4* env = (float4*)ent_next;
        env[g * 16 + lane] = en;
    }
    float4* outv = (float4*)out;
    float4 o = outv[g * 16 + lane];
    outv[g * 16 + lane] = f4_add(o, en);
}

// ---------- fused per-hop user LWS ----------
__global__ __launch_bounds__(256) void k_user(
    const float* __restrict__ ent, const float* __restrict__ usr,
    const int* __restrict__ rp, const int* __restrict__ sorted,
    float* __restrict__ usr_next, int do_store, float* __restrict__ out)
{
    int g = (blockIdx.x * blockDim.x + threadIdx.x) >> 4;
    int lane = threadIdx.x & 15;
    if (g >= N_USR) return;
    int start = rp[g], end = rp[g + 1];
    const float4* entv = (const float4*)ent;
    const float4* usrv = (const float4*)usr;
    float4 uh = usrv[g * 16 + lane];

    float cnt = (float)(end - start);
    float inv = 1.f / fmaxf(cnt, 1.f);

    // iter 0
    float4 acc = f4_zero();
    for (int e = start; e < end; e++) {
        float4 x = entv[sorted[e] * 16 + lane];
        acc = f4_add(acc, x);
    }
    float4 u = f4_scale(inv, acc);
    float sq = red16(f4_dot(u, u));
    float4 u1 = f4_add(squash4(u, sq), uh);

    // iter 1: fresh neigh; scale = dot(u1, x)
    acc = f4_zero();
    for (int e = start; e < end; e++) {
        float4 x = entv[sorted[e] * 16 + lane];
        float d = red16(f4_dot(u1, x));
        acc = f4_fma(d, x, acc);
    }
    u = f4_scale(inv, acc);
    sq = red16(f4_dot(u, u));
    float4 u2 = f4_add(squash4(u, sq), uh);

    // iter 2: fresh neigh; scale = dot(u2, x); no squash
    acc = f4_zero();
    for (int e = start; e < end; e++) {
        float4 x = entv[sorted[e] * 16 + lane];
        float d = red16(f4_dot(u2, x));
        acc = f4_fma(d, x, acc);
    }
    float4 u3 = f4_add(f4_scale(inv, acc), uh);

    sq = red16(f4_dot(u3, u3));
    float n = sqrtf(sq);
    float4 un = f4_scale(1.f / fmaxf(n, EPSF), u3);
    if (do_store) {
        float4* unv = (float4*)usr_next;
        unv[g * 16 + lane] = un;
    }
    float4* outv = (float4*)out;
    float4 o = outv[g * 16 + lane];
    outv[g * 16 + lane] = f4_add(o, un);
}

// ---------- launch ----------
extern "C" void kernel_launch(void* const* d_in, const int* in_sizes, int n_in,
                              void* d_out, int out_size, void* d_ws, size_t ws_size,
                              hipStream_t stream)
{
    const float* entity_emb = (const float*)d_in[0];
    const float* user_emb   = (const float*)d_in[1];
    const float* latent     = (const float*)d_in[2];
    const float* rel_w      = (const float*)d_in[3];
    const float* agg_w      = (const float*)d_in[4];
    const int* edge_index   = (const int*)d_in[5];
    const int* edge_type    = (const int*)d_in[6];
    const int* user_index   = (const int*)d_in[7];
    const int* item_index   = (const int*)d_in[8];
    float* out = (float*)d_out;

    char* ws = (char*)d_ws;
    size_t off = 0;
    auto alloc = [&](size_t bytes) -> void* {
        void* p = ws + off;
        off += (bytes + 255) / 256 * 256;
        return p;
    };
    float* entA  = (float*)alloc((size_t)N_ENT * DIM * 4);
    float* usrA  = (float*)alloc((size_t)N_USR * DIM * 4);
    float* wsoft = (float*)alloc(8 * 4);
    int* remap   = (int*)alloc(16 * 4);
    int* ecnt    = (int*)alloc((size_t)N_ENT * 4);
    int* erp     = (int*)alloc((size_t)(N_ENT + 1) * 4);
    int* ecur    = (int*)alloc((size_t)N_ENT * 4);
    int* eexcl   = (int*)alloc((size_t)N_ENT * 4);
    int* ebsum   = (int*)alloc(2048 * 4);
    int* esorted = (int*)alloc((size_t)NE * 4);
    int* ucnt    = (int*)alloc((size_t)N_USR * 4);
    int* urp     = (int*)alloc((size_t)(N_USR + 1) * 4);
    int* ucur    = (int*)alloc((size_t)N_USR * 4);
    int* uexcl   = (int*)alloc((size_t)N_USR * 4);
    int* ubsum   = (int*)alloc(2048 * 4);
    int* usorted = (int*)alloc((size_t)NI_ * 4);

    const int* head = edge_index;
    const int* tail = edge_index + NE;

    hipMemsetAsync(ecnt, 0, (size_t)N_ENT * 4, stream);
    hipMemsetAsync(ucnt, 0, (size_t)N_USR * 4, stream);

    k_remap<<<1, 32, 0, stream>>>(rel_w, latent, remap);
    k_soft<<<1, 32, 0, stream>>>(agg_w, wsoft);

    k_count<<<(NE + 255) / 256, 256, 0, stream>>>(head, NE, ecnt);
    k_count<<<(NI_ + 255) / 256, 256, 0, stream>>>(user_index, NI_, ucnt);

    int nbE = (N_ENT + SCAN_B - 1) / SCAN_B;
    int nbU = (N_USR + SCAN_B - 1) / SCAN_B;
    k_scan1<<<nbE, SCAN_B, 0, stream>>>(ecnt, eexcl, ebsum, N_ENT);
    k_scan2<<<1, SCAN_B, 0, stream>>>(ebsum, nbE);
    k_scan3<<<nbE, SCAN_B, 0, stream>>>(eexcl, ebsum, ecnt, erp, ecur, N_ENT);
    k_scan1<<<nbU, SCAN_B, 0, stream>>>(ucnt, uexcl, ubsum, N_USR);
    k_scan2<<<1, SCAN_B, 0, stream>>>(ubsum, nbU);
    k_scan3<<<nbU, SCAN_B, 0, stream>>>(uexcl, ubsum, ucnt, urp, ucur, N_USR);

    k_scatter_ent<<<(NE + 255) / 256, 256, 0, stream>>>(head, tail, edge_type, remap, ecur, esorted);
    k_scatter_usr<<<(NI_ + 255) / 256, 256, 0, stream>>>(user_index, item_index, ucur, usorted);

    // out = [entity_emb ; user_emb] residual base
    hipMemcpyAsync(out, entity_emb, (size_t)N_ENT * DIM * 4, hipMemcpyDeviceToDevice, stream);
    hipMemcpyAsync(out + (size_t)N_ENT * DIM, user_emb, (size_t)N_USR * DIM * 4,
                   hipMemcpyDeviceToDevice, stream);

    const float* ec = entity_emb;
    const float* uc = user_emb;
    for (int hop = 0; hop < 2; hop++) {
        int do_store = (hop == 0);  // last hop's ent/usr never re-read
        k_entity<<<(N_ENT * 16 + 255) / 256, 256, 0, stream>>>(
            ec, erp, esorted, wsoft, hop, entA, do_store, out);
        k_user<<<(N_USR * 16 + 255) / 256, 256, 0, stream>>>(
            ec, uc, urp, usorted, usrA, do_store, out + (size_t)N_ENT * DIM);
        ec = entA;
        uc = usrA;
    }
}

// Round 2
// 1059.652 us; speedup vs baseline: 1.1683x; 1.1683x over previous
//
#include <hip/hip_runtime.h>

#define N_ENT 200000
#define N_USR 100000
#define DIM 64
#define NE 1500000
#define NI_ 1000000
#define NREL1 10     // N_REL - 1
#define NVIRT 3
#define EPSF 1e-12f
#define SCAN_B 1024
#define RE 12        // cached edges/group, entity (Poisson mean 7.5)
#define RU 16        // cached edges/group, user   (Poisson mean 10)

// ---------- float4 helpers ----------
__device__ __forceinline__ float4 f4_zero() { return make_float4(0.f, 0.f, 0.f, 0.f); }
__device__ __forceinline__ float4 f4_add(float4 a, float4 b) {
    return make_float4(a.x + b.x, a.y + b.y, a.z + b.z, a.w + b.w);
}
__device__ __forceinline__ float4 f4_scale(float s, float4 a) {
    return make_float4(s * a.x, s * a.y, s * a.z, s * a.w);
}
__device__ __forceinline__ float4 f4_fma(float s, float4 a, float4 b) { // s*a + b
    return make_float4(fmaf(s, a.x, b.x), fmaf(s, a.y, b.y), fmaf(s, a.z, b.z), fmaf(s, a.w, b.w));
}
__device__ __forceinline__ float f4_dot(float4 a, float4 b) {
    return a.x * b.x + a.y * b.y + a.z * b.z + a.w * b.w;
}
// sum across the 16-lane subgroup (wave64 = 4 aligned segments of 16)
__device__ __forceinline__ float red16(float v) {
    v += __shfl_xor(v, 1, 16);
    v += __shfl_xor(v, 2, 16);
    v += __shfl_xor(v, 4, 16);
    v += __shfl_xor(v, 8, 16);
    return v;
}
__device__ __forceinline__ float4 squash4(float4 u, float sq) {
    float n = sqrtf(sq);
    float s = sq / ((sq + 1.f) * fmaxf(n, EPSF));
    return f4_scale(s, u);
}

// ---------- tiny precompute kernels ----------
__global__ void k_remap(const float* __restrict__ rw, const float* __restrict__ lat,
                        int* __restrict__ remap) {
    int r = threadIdx.x;
    if (r < NREL1) {
        float best = -3.4e38f; int bi = 0;
        for (int j = 0; j < NVIRT; j++) {
            float s = 0.f;
            for (int d = 0; d < DIM; d++) s += rw[r * DIM + d] * lat[j * DIM + d];
            if (s > best) { best = s; bi = j; }
        }
        remap[r] = bi;
    }
}

__global__ void k_soft(const float* __restrict__ aw, float* __restrict__ wsoft) {
    int h = threadIdx.x;
    if (h < 2) {
        float a0 = aw[h * 3 + 0], a1 = aw[h * 3 + 1], a2 = aw[h * 3 + 2];
        float m = fmaxf(a0, fmaxf(a1, a2));
        float e0 = expf(a0 - m), e1 = expf(a1 - m), e2 = expf(a2 - m);
        float s = e0 + e1 + e2;
        wsoft[h * 3 + 0] = e0 / s; wsoft[h * 3 + 1] = e1 / s; wsoft[h * 3 + 2] = e2 / s;
    }
}

// ---------- CSR build ----------
__global__ void k_count(const int* __restrict__ idx, int n, int* __restrict__ cnt) {
    int i = blockIdx.x * blockDim.x + threadIdx.x;
    if (i < n) atomicAdd(&cnt[idx[i]], 1);
}

__global__ void k_scan1(const int* __restrict__ in, int* __restrict__ excl,
                        int* __restrict__ bsum, int n) {
    __shared__ int s[SCAN_B];
    int tid = threadIdx.x, gid = blockIdx.x * SCAN_B + tid;
    int v = (gid < n) ? in[gid] : 0;
    s[tid] = v; __syncthreads();
    for (int off = 1; off < SCAN_B; off <<= 1) {
        int t = 0;
        if (tid >= off) t = s[tid - off];
        __syncthreads();
        s[tid] += t;
        __syncthreads();
    }
    if (gid < n) excl[gid] = s[tid] - v;
    if (tid == SCAN_B - 1) bsum[blockIdx.x] = s[tid];
}

__global__ void k_scan2(int* __restrict__ bsum, int nb) {
    __shared__ int s[SCAN_B];
    int tid = threadIdx.x;
    int v = (tid < nb) ? bsum[tid] : 0;
    s[tid] = v; __syncthreads();
    for (int off = 1; off < SCAN_B; off <<= 1) {
        int t = 0;
        if (tid >= off) t = s[tid - off];
        __syncthreads();
        s[tid] += t;
        __syncthreads();
    }
    if (tid < nb) bsum[tid] = s[tid] - v;  // exclusive
}

__global__ void k_scan3(const int* __restrict__ excl, const int* __restrict__ bsum,
                        const int* __restrict__ cnt, int* __restrict__ rp,
                        int* __restrict__ cur, int n) {
    int gid = blockIdx.x * SCAN_B + threadIdx.x;
    if (gid < n) {
        int v = excl[gid] + bsum[blockIdx.x];
        rp[gid] = v;
        cur[gid] = v;
        if (gid == n - 1) rp[n] = v + cnt[gid];
    }
}

__global__ void k_scatter_ent(const int* __restrict__ head, const int* __restrict__ tail,
                              const int* __restrict__ etype, const int* __restrict__ remap,
                              int* __restrict__ cur, int* __restrict__ sorted) {
    int e = blockIdx.x * blockDim.x + threadIdx.x;
    if (e < NE) {
        int h = head[e];
        int v = remap[etype[e] - 1];
        int pos = atomicAdd(&cur[h], 1);
        sorted[pos] = tail[e] | (v << 18);   // tail < 2^18
    }
}

__global__ void k_scatter_usr(const int* __restrict__ ui, const int* __restrict__ ii,
                              int* __restrict__ cur, int* __restrict__ sorted) {
    int e = blockIdx.x * blockDim.x + threadIdx.x;
    if (e < NI_) {
        int pos = atomicAdd(&cur[ui[e]], 1);
        sorted[pos] = ii[e];
    }
}

// ---------- fused per-hop entity LWS, register-cached neighbor rows ----------
__global__ __launch_bounds__(256, 4) void k_entity(
    const float* __restrict__ ent, const int* __restrict__ rp,
    const int* __restrict__ sorted, const float* __restrict__ wsoft,
    int hop, float* __restrict__ ent_next, int do_store, int first,
    float* __restrict__ out)
{
    int g = (blockIdx.x * blockDim.x + threadIdx.x) >> 4;
    int lane = threadIdx.x & 15;
    if (g >= N_ENT) return;
    int start = rp[g], end = rp[g + 1];
    int deg = end - start;
    const float4* entv = (const float4*)ent;
    float4 eh = entv[g * 16 + lane];

    int pk[RE];
    float4 xc[RE];
    float4 a0 = f4_zero(), a1 = f4_zero(), a2 = f4_zero();
    float c0 = 0.f, c1 = 0.f, c2 = 0.f;

    // ---- iter 0 + cache fill
    #pragma unroll
    for (int r = 0; r < RE; r++) {
        if (r < deg) {
            int p = sorted[start + r];
            pk[r] = p;
            float4 x = entv[(p & 0x3FFFF) * 16 + lane];
            xc[r] = x;
            int v = p >> 18;
            if (v == 0)      { a0 = f4_add(a0, x); c0 += 1.f; }
            else if (v == 1) { a1 = f4_add(a1, x); c1 += 1.f; }
            else             { a2 = f4_add(a2, x); c2 += 1.f; }
        }
    }
    for (int e = start + RE; e < end; e++) {
        int p = sorted[e];
        float4 x = entv[(p & 0x3FFFF) * 16 + lane];
        int v = p >> 18;
        if (v == 0)      { a0 = f4_add(a0, x); c0 += 1.f; }
        else if (v == 1) { a1 = f4_add(a1, x); c1 += 1.f; }
        else             { a2 = f4_add(a2, x); c2 += 1.f; }
    }
    float i0 = 1.f / fmaxf(c0, 1.f), i1 = 1.f / fmaxf(c1, 1.f), i2 = 1.f / fmaxf(c2, 1.f);
    float4 u; float sq;
    u = f4_scale(i0, a0); sq = red16(f4_dot(u, u)); float4 u10 = f4_add(squash4(u, sq), eh);
    u = f4_scale(i1, a1); sq = red16(f4_dot(u, u)); float4 u11 = f4_add(squash4(u, sq), eh);
    u = f4_scale(i2, a2); sq = red16(f4_dot(u, u)); float4 u12 = f4_add(squash4(u, sq), eh);

    // ---- iter 1: scale = dot(u1_v, x)
    a0 = a1 = a2 = f4_zero();
    #pragma unroll
    for (int r = 0; r < RE; r++) {
        if (r < deg) {
            int v = pk[r] >> 18;
            float4 x = xc[r];
            float4 uv = (v == 0) ? u10 : ((v == 1) ? u11 : u12);
            float d = red16(f4_dot(uv, x));
            if (v == 0)      a0 = f4_fma(d, x, a0);
            else if (v == 1) a1 = f4_fma(d, x, a1);
            else             a2 = f4_fma(d, x, a2);
        }
    }
    for (int e = start + RE; e < end; e++) {
        int p = sorted[e];
        float4 x = entv[(p & 0x3FFFF) * 16 + lane];
        int v = p >> 18;
        float4 uv = (v == 0) ? u10 : ((v == 1) ? u11 : u12);
        float d = red16(f4_dot(uv, x));
        if (v == 0)      a0 = f4_fma(d, x, a0);
        else if (v == 1) a1 = f4_fma(d, x, a1);
        else             a2 = f4_fma(d, x, a2);
    }
    u = f4_scale(i0, a0); sq = red16(f4_dot(u, u)); float4 u20 = f4_add(squash4(u, sq), eh);
    u = f4_scale(i1, a1); sq = red16(f4_dot(u, u)); float4 u21 = f4_add(squash4(u, sq), eh);
    u = f4_scale(i2, a2); sq = red16(f4_dot(u, u)); float4 u22 = f4_add(squash4(u, sq), eh);

    // ---- iter 2: scale = d1^2 * d2 (cumulative), no squash
    a0 = a1 = a2 = f4_zero();
    #pragma unroll
    for (int r = 0; r < RE; r++) {
        if (r < deg) {
            int v = pk[r] >> 18;
            float4 x = xc[r];
            float4 uv1 = (v == 0) ? u10 : ((v == 1) ? u11 : u12);
            float4 uv2 = (v == 0) ? u20 : ((v == 1) ? u21 : u22);
            float pd1 = f4_dot(uv1, x);
            float pd2 = f4_dot(uv2, x);
            float d1 = red16(pd1);
            float d2 = red16(pd2);
            float s = d1 * d1 * d2;
            if (v == 0)      a0 = f4_fma(s, x, a0);
            else if (v == 1) a1 = f4_fma(s, x, a1);
            else             a2 = f4_fma(s, x, a2);
        }
    }
    for (int e = start + RE; e < end; e++) {
        int p = sorted[e];
        float4 x = entv[(p & 0x3FFFF) * 16 + lane];
        int v = p >> 18;
        float4 uv1 = (v == 0) ? u10 : ((v == 1) ? u11 : u12);
        float4 uv2 = (v == 0) ? u20 : ((v == 1) ? u21 : u22);
        float pd1 = f4_dot(uv1, x);
        float pd2 = f4_dot(uv2, x);
        float d1 = red16(pd1);
        float d2 = red16(pd2);
        float s = d1 * d1 * d2;
        if (v == 0)      a0 = f4_fma(s, x, a0);
        else if (v == 1) a1 = f4_fma(s, x, a1);
        else             a2 = f4_fma(s, x, a2);
    }

    float w0 = wsoft[hop * 3 + 0], w1 = wsoft[hop * 3 + 1], w2 = wsoft[hop * 3 + 2];
    float4 agg = f4_zero();
    agg = f4_fma(w0, f4_add(f4_scale(i0, a0), eh), agg);
    agg = f4_fma(w1, f4_add(f4_scale(i1, a1), eh), agg);
    agg = f4_fma(w2, f4_add(f4_scale(i2, a2), eh), agg);
    sq = red16(f4_dot(agg, agg));
    float nn = sqrtf(sq);
    float4 en = f4_scale(1.f / fmaxf(nn, EPSF), agg);
    if (do_store) {
        float4* env = (float4*)ent_next;
        env[g * 16 + lane] = en;
    }
    float4* outv = (float4*)out;
    // hop 0: out = base_row + en (base row == eh, no out read, no memcpy needed)
    float4 base = first ? eh : outv[g * 16 + lane];
    outv[g * 16 + lane] = f4_add(base, en);
}

// ---------- fused per-hop user LWS, register-cached neighbor rows ----------
__global__ __launch_bounds__(256, 4) void k_user(
    const float* __restrict__ ent, const float* __restrict__ usr,
    const int* __restrict__ rp, const int* __restrict__ sorted,
    float* __restrict__ usr_next, int do_store, int first, float* __restrict__ out)
{
    int g = (blockIdx.x * blockDim.x + threadIdx.x) >> 4;
    int lane = threadIdx.x & 15;
    if (g >= N_USR) return;
    int start = rp[g], end = rp[g + 1];
    int deg = end - start;
    const float4* entv = (const float4*)ent;
    const float4* usrv = (const float4*)usr;
    float4 uh = usrv[g * 16 + lane];

    float inv = 1.f / fmaxf((float)deg, 1.f);
    float4 xc[RU];

    // iter 0 + cache fill
    float4 acc = f4_zero();
    #pragma unroll
    for (int r = 0; r < RU; r++) {
        if (r < deg) {
            float4 x = entv[sorted[start + r] * 16 + lane];
            xc[r] = x;
            acc = f4_add(acc, x);
        }
    }
    for (int e = start + RU; e < end; e++) {
        acc = f4_add(acc, entv[sorted[e] * 16 + lane]);
    }
    float4 u = f4_scale(inv, acc);
    float sq = red16(f4_dot(u, u));
    float4 u1 = f4_add(squash4(u, sq), uh);

    // iter 1
    acc = f4_zero();
    #pragma unroll
    for (int r = 0; r < RU; r++) {
        if (r < deg) {
            float4 x = xc[r];
            float d = red16(f4_dot(u1, x));
            acc = f4_fma(d, x, acc);
        }
    }
    for (int e = start + RU; e < end; e++) {
        float4 x = entv[sorted[e] * 16 + lane];
        float d = red16(f4_dot(u1, x));
        acc = f4_fma(d, x, acc);
    }
    u = f4_scale(inv, acc);
    sq = red16(f4_dot(u, u));
    float4 u2 = f4_add(squash4(u, sq), uh);

    // iter 2
    acc = f4_zero();
    #pragma unroll
    for (int r = 0; r < RU; r++) {
        if (r < deg) {
            float4 x = xc[r];
            float d = red16(f4_dot(u2, x));
            acc = f4_fma(d, x, acc);
        }
    }
    for (int e = start + RU; e < end; e++) {
        float4 x = entv[sorted[e] * 16 + lane];
        float d = red16(f4_dot(u2, x));
        acc = f4_fma(d, x, acc);
    }
    float4 u3 = f4_add(f4_scale(inv, acc), uh);

    sq = red16(f4_dot(u3, u3));
    float nn = sqrtf(sq);
    float4 un = f4_scale(1.f / fmaxf(nn, EPSF), u3);
    if (do_store) {
        float4* unv = (float4*)usr_next;
        unv[g * 16 + lane] = un;
    }
    float4* outv = (float4*)out;
    float4 base = first ? uh : outv[g * 16 + lane];
    outv[g * 16 + lane] = f4_add(base, un);
}

// ---------- launch ----------
extern "C" void kernel_launch(void* const* d_in, const int* in_sizes, int n_in,
                              void* d_out, int out_size, void* d_ws, size_t ws_size,
                              hipStream_t stream)
{
    const float* entity_emb = (const float*)d_in[0];
    const float* user_emb   = (const float*)d_in[1];
    const float* latent     = (const float*)d_in[2];
    const float* rel_w      = (const float*)d_in[3];
    const float* agg_w      = (const float*)d_in[4];
    const int* edge_index   = (const int*)d_in[5];
    const int* edge_type    = (const int*)d_in[6];
    const int* user_index   = (const int*)d_in[7];
    const int* item_index   = (const int*)d_in[8];
    float* out = (float*)d_out;

    char* ws = (char*)d_ws;
    size_t off = 0;
    auto alloc = [&](size_t bytes) -> void* {
        void* p = ws + off;
        off += (bytes + 255) / 256 * 256;
        return p;
    };
    float* entA  = (float*)alloc((size_t)N_ENT * DIM * 4);
    float* usrA  = (float*)alloc((size_t)N_USR * DIM * 4);
    float* wsoft = (float*)alloc(8 * 4);
    int* remap   = (int*)alloc(16 * 4);
    int* ecnt    = (int*)alloc((size_t)N_ENT * 4);
    int* erp     = (int*)alloc((size_t)(N_ENT + 1) * 4);
    int* ecur    = (int*)alloc((size_t)N_ENT * 4);
    int* eexcl   = (int*)alloc((size_t)N_ENT * 4);
    int* ebsum   = (int*)alloc(2048 * 4);
    int* esorted = (int*)alloc((size_t)NE * 4);
    int* ucnt    = (int*)alloc((size_t)N_USR * 4);
    int* urp     = (int*)alloc((size_t)(N_USR + 1) * 4);
    int* ucur    = (int*)alloc((size_t)N_USR * 4);
    int* uexcl   = (int*)alloc((size_t)N_USR * 4);
    int* ubsum   = (int*)alloc(2048 * 4);
    int* usorted = (int*)alloc((size_t)NI_ * 4);

    const int* head = edge_index;
    const int* tail = edge_index + NE;

    hipMemsetAsync(ecnt, 0, (size_t)N_ENT * 4, stream);
    hipMemsetAsync(ucnt, 0, (size_t)N_USR * 4, stream);

    k_remap<<<1, 32, 0, stream>>>(rel_w, latent, remap);
    k_soft<<<1, 32, 0, stream>>>(agg_w, wsoft);

    k_count<<<(NE + 255) / 256, 256, 0, stream>>>(head, NE, ecnt);
    k_count<<<(NI_ + 255) / 256, 256, 0, stream>>>(user_index, NI_, ucnt);

    int nbE = (N_ENT + SCAN_B - 1) / SCAN_B;
    int nbU = (N_USR + SCAN_B - 1) / SCAN_B;
    k_scan1<<<nbE, SCAN_B, 0, stream>>>(ecnt, eexcl, ebsum, N_ENT);
    k_scan2<<<1, SCAN_B, 0, stream>>>(ebsum, nbE);
    k_scan3<<<nbE, SCAN_B, 0, stream>>>(eexcl, ebsum, ecnt, erp, ecur, N_ENT);
    k_scan1<<<nbU, SCAN_B, 0, stream>>>(ucnt, uexcl, ubsum, N_USR);
    k_scan2<<<1, SCAN_B, 0, stream>>>(ubsum, nbU);
    k_scan3<<<nbU, SCAN_B, 0, stream>>>(uexcl, ubsum, ucnt, urp, ucur, N_USR);

    k_scatter_ent<<<(NE + 255) / 256, 256, 0, stream>>>(head, tail, edge_type, remap, ecur, esorted);
    k_scatter_usr<<<(NI_ + 255) / 256, 256, 0, stream>>>(user_index, item_index, ucur, usorted);

    const float* ec = entity_emb;
    const float* uc = user_emb;
    for (int hop = 0; hop < 2; hop++) {
        int do_store = (hop == 0);  // last hop's ent/usr never re-read
        int first = (hop == 0);     // hop 0 writes out = base + en (no out read)
        k_entity<<<(N_ENT * 16 + 255) / 256, 256, 0, stream>>>(
            ec, erp, esorted, wsoft, hop, entA, do_store, first, out);
        k_user<<<(N_USR * 16 + 255) / 256, 256, 0, stream>>>(
            ec, uc, urp, usorted, usrA, do_store, first, out + (size_t)N_ENT * DIM);
        ec = entA;
        uc = usrA;
    }
}

// Round 3
// 890.415 us; speedup vs baseline: 1.3904x; 1.1901x over previous
//
#include <hip/hip_runtime.h>

#define N_ENT 200000
#define N_USR 100000
#define NT    300000      // N_ENT + N_USR
#define DIM 64
#define NE 1500000
#define NI_ 1000000
#define NTE 2500000       // NE + NI_
#define NREL1 10
#define NVIRT 3
#define EPSF 1e-12f
#define SCAN_B 1024
#define RE 8              // cached neighbor rows per entity group
#define RU 12             // cached neighbor rows per user group

// ---------- float4 helpers ----------
__device__ __forceinline__ float4 f4_zero() { return make_float4(0.f, 0.f, 0.f, 0.f); }
__device__ __forceinline__ float4 f4_add(float4 a, float4 b) {
    return make_float4(a.x + b.x, a.y + b.y, a.z + b.z, a.w + b.w);
}
__device__ __forceinline__ float4 f4_scale(float s, float4 a) {
    return make_float4(s * a.x, s * a.y, s * a.z, s * a.w);
}
__device__ __forceinline__ float4 f4_fma(float s, float4 a, float4 b) {
    return make_float4(fmaf(s, a.x, b.x), fmaf(s, a.y, b.y), fmaf(s, a.z, b.z), fmaf(s, a.w, b.w));
}
__device__ __forceinline__ float f4_dot(float4 a, float4 b) {
    return a.x * b.x + a.y * b.y + a.z * b.z + a.w * b.w;
}
__device__ __forceinline__ float red16(float v) {
    v += __shfl_xor(v, 1, 16);
    v += __shfl_xor(v, 2, 16);
    v += __shfl_xor(v, 4, 16);
    v += __shfl_xor(v, 8, 16);
    return v;
}
__device__ __forceinline__ float4 squash4(float4 u, float sq) {
    float n = sqrtf(sq);
    float s = sq / ((sq + 1.f) * fmaxf(n, EPSF));
    return f4_scale(s, u);
}

// ---------- tiny precompute ----------
__global__ void k_remap(const float* __restrict__ rw, const float* __restrict__ lat,
                        int* __restrict__ remap) {
    int r = threadIdx.x;
    if (r < NREL1) {
        float best = -3.4e38f; int bi = 0;
        for (int j = 0; j < NVIRT; j++) {
            float s = 0.f;
            for (int d = 0; d < DIM; d++) s += rw[r * DIM + d] * lat[j * DIM + d];
            if (s > best) { best = s; bi = j; }
        }
        remap[r] = bi;
    }
}

__global__ void k_soft(const float* __restrict__ aw, float* __restrict__ wsoft) {
    int h = threadIdx.x;
    if (h < 2) {
        float a0 = aw[h * 3 + 0], a1 = aw[h * 3 + 1], a2 = aw[h * 3 + 2];
        float m = fmaxf(a0, fmaxf(a1, a2));
        float e0 = expf(a0 - m), e1 = expf(a1 - m), e2 = expf(a2 - m);
        float s = e0 + e1 + e2;
        wsoft[h * 3 + 0] = e0 / s; wsoft[h * 3 + 1] = e1 / s; wsoft[h * 3 + 2] = e2 / s;
    }
}

// ---------- combined CSR build (entity keys [0,N_ENT), user keys [N_ENT,NT)) ----------
__global__ void k_count_all(const int* __restrict__ head, const int* __restrict__ uidx,
                            int* __restrict__ cnt) {
    int i = blockIdx.x * blockDim.x + threadIdx.x;
    if (i < NE) atomicAdd(&cnt[head[i]], 1);
    else if (i < NTE) atomicAdd(&cnt[N_ENT + uidx[i - NE]], 1);
}

__global__ void k_scan1(const int* __restrict__ in, int* __restrict__ excl,
                        int* __restrict__ bsum, int n) {
    __shared__ int s[SCAN_B];
    int tid = threadIdx.x, gid = blockIdx.x * SCAN_B + tid;
    int v = (gid < n) ? in[gid] : 0;
    s[tid] = v; __syncthreads();
    for (int off = 1; off < SCAN_B; off <<= 1) {
        int t = 0;
        if (tid >= off) t = s[tid - off];
        __syncthreads();
        s[tid] += t;
        __syncthreads();
    }
    if (gid < n) excl[gid] = s[tid] - v;
    if (tid == SCAN_B - 1) bsum[blockIdx.x] = s[tid];
}

__global__ void k_scan2(int* __restrict__ bsum, int nb) {
    __shared__ int s[SCAN_B];
    int tid = threadIdx.x;
    int v = (tid < nb) ? bsum[tid] : 0;
    s[tid] = v; __syncthreads();
    for (int off = 1; off < SCAN_B; off <<= 1) {
        int t = 0;
        if (tid >= off) t = s[tid - off];
        __syncthreads();
        s[tid] += t;
        __syncthreads();
    }
    if (tid < nb) bsum[tid] = s[tid] - v;
}

__global__ void k_scan3(const int* __restrict__ excl, const int* __restrict__ bsum,
                        const int* __restrict__ cnt, int* __restrict__ rp,
                        int* __restrict__ cur, int n) {
    int gid = blockIdx.x * SCAN_B + threadIdx.x;
    if (gid < n) {
        int v = excl[gid] + bsum[blockIdx.x];
        rp[gid] = v;
        cur[gid] = v;
        if (gid == n - 1) rp[n] = v + cnt[gid];
    }
}

__global__ void k_scatter_all(const int* __restrict__ head, const int* __restrict__ tail,
                              const int* __restrict__ etype, const int* __restrict__ remap,
                              const int* __restrict__ uidx, const int* __restrict__ iidx,
                              int* __restrict__ cur, int* __restrict__ sorted) {
    int i = blockIdx.x * blockDim.x + threadIdx.x;
    if (i < NE) {
        int v = remap[etype[i] - 1];
        int pos = atomicAdd(&cur[head[i]], 1);
        sorted[pos] = tail[i] | (v << 18);   // tail < 2^18
    } else if (i < NTE) {
        int j = i - NE;
        int pos = atomicAdd(&cur[N_ENT + uidx[j]], 1);
        sorted[pos] = iidx[j];
    }
}

// ---------- merged per-hop LWS kernel: entity blocks then user blocks ----------
#define NBLK_E (N_ENT / 16)   // 12500
#define NBLK_U (N_USR / 16)   // 6250

__global__ __launch_bounds__(256, 4) void k_hop(
    const float* __restrict__ ent, const float* __restrict__ usr,
    const int* __restrict__ rp, const int* __restrict__ sorted,
    const float* __restrict__ wsoft, int hop,
    float* __restrict__ ent_next, float* __restrict__ usr_next,
    int do_store, int first,
    float* __restrict__ outE, float* __restrict__ outU)
{
    int lane = threadIdx.x & 15;
    const float4* entv = (const float4*)ent;

    if (blockIdx.x < NBLK_E) {
        // ================= entity path =================
        int g = blockIdx.x * 16 + (threadIdx.x >> 4);
        int start = rp[g], end = rp[g + 1];
        int deg = end - start;
        int deg16 = (deg < 16) ? deg : 16;
        float4 eh = entv[g * 16 + lane];

        // lane-distributed header cache: lane r holds edge r's packed (tail|v<<18)
        int myp = 0;
        if (lane < deg16) myp = sorted[start + lane];
        int myv = myp >> 18;
        int segsh = threadIdx.x & 48;  // 16-lane segment base within wave
        unsigned long long b0 = __ballot(lane < deg16 && myv == 0);
        unsigned long long b1 = __ballot(lane < deg16 && myv == 1);
        unsigned long long b2 = __ballot(lane < deg16 && myv == 2);
        float c0 = (float)__popc((unsigned)((b0 >> segsh) & 0xFFFFull));
        float c1 = (float)__popc((unsigned)((b1 >> segsh) & 0xFFFFull));
        float c2 = (float)__popc((unsigned)((b2 >> segsh) & 0xFFFFull));

        float4 xc[RE];
        float4 a0 = f4_zero(), a1 = f4_zero(), a2 = f4_zero();

        // ---- iter 0 (+ row cache fill for r < RE)
        #pragma unroll
        for (int r = 0; r < RE; r++) {
            if (r < deg) {
                int p = __shfl(myp, r, 16);
                float4 x = entv[(p & 0x3FFFF) * 16 + lane];
                xc[r] = x;
                int v = p >> 18;
                if (v == 0)      a0 = f4_add(a0, x);
                else if (v == 1) a1 = f4_add(a1, x);
                else             a2 = f4_add(a2, x);
            }
        }
        #pragma unroll
        for (int r = RE; r < 16; r++) {
            if (r < deg) {
                int p = __shfl(myp, r, 16);
                float4 x = entv[(p & 0x3FFFF) * 16 + lane];
                int v = p >> 18;
                if (v == 0)      a0 = f4_add(a0, x);
                else if (v == 1) a1 = f4_add(a1, x);
                else             a2 = f4_add(a2, x);
            }
        }
        for (int e = start + 16; e < end; e++) {
            int p = sorted[e];
            float4 x = entv[(p & 0x3FFFF) * 16 + lane];
            int v = p >> 18;
            if (v == 0)      { a0 = f4_add(a0, x); c0 += 1.f; }
            else if (v == 1) { a1 = f4_add(a1, x); c1 += 1.f; }
            else             { a2 = f4_add(a2, x); c2 += 1.f; }
        }
        float i0 = 1.f / fmaxf(c0, 1.f), i1 = 1.f / fmaxf(c1, 1.f), i2 = 1.f / fmaxf(c2, 1.f);
        float4 u; float sq;
        u = f4_scale(i0, a0); sq = red16(f4_dot(u, u)); float4 u10 = f4_add(squash4(u, sq), eh);
        u = f4_scale(i1, a1); sq = red16(f4_dot(u, u)); float4 u11 = f4_add(squash4(u, sq), eh);
        u = f4_scale(i2, a2); sq = red16(f4_dot(u, u)); float4 u12 = f4_add(squash4(u, sq), eh);

        // ---- iter 1: scale = d1 = dot(u1_v, x); cache d1 lane-distributed
        float d1me = 0.f;
        a0 = a1 = a2 = f4_zero();
        #pragma unroll
        for (int r = 0; r < RE; r++) {
            if (r < deg) {
                int p = __shfl(myp, r, 16);
                int v = p >> 18;
                float4 x = xc[r];
                float4 uv = (v == 0) ? u10 : ((v == 1) ? u11 : u12);
                float d1 = red16(f4_dot(uv, x));
                if (lane == r) d1me = d1;
                if (v == 0)      a0 = f4_fma(d1, x, a0);
                else if (v == 1) a1 = f4_fma(d1, x, a1);
                else             a2 = f4_fma(d1, x, a2);
            }
        }
        #pragma unroll
        for (int r = RE; r < 16; r++) {
            if (r < deg) {
                int p = __shfl(myp, r, 16);
                int v = p >> 18;
                float4 x = entv[(p & 0x3FFFF) * 16 + lane];
                float4 uv = (v == 0) ? u10 : ((v == 1) ? u11 : u12);
                float d1 = red16(f4_dot(uv, x));
                if (lane == r) d1me = d1;
                if (v == 0)      a0 = f4_fma(d1, x, a0);
                else if (v == 1) a1 = f4_fma(d1, x, a1);
                else             a2 = f4_fma(d1, x, a2);
            }
        }
        for (int e = start + 16; e < end; e++) {
            int p = sorted[e];
            int v = p >> 18;
            float4 x = entv[(p & 0x3FFFF) * 16 + lane];
            float4 uv = (v == 0) ? u10 : ((v == 1) ? u11 : u12);
            float d1 = red16(f4_dot(uv, x));
            if (v == 0)      a0 = f4_fma(d1, x, a0);
            else if (v == 1) a1 = f4_fma(d1, x, a1);
            else             a2 = f4_fma(d1, x, a2);
        }
        u = f4_scale(i0, a0); sq = red16(f4_dot(u, u)); float4 u20 = f4_add(squash4(u, sq), eh);
        u = f4_scale(i1, a1); sq = red16(f4_dot(u, u)); float4 u21 = f4_add(squash4(u, sq), eh);
        u = f4_scale(i2, a2); sq = red16(f4_dot(u, u)); float4 u22 = f4_add(squash4(u, sq), eh);

        // ---- iter 2: s = d1^2 * d2 * (w_v * inv_v), single accumulator
        float w0 = wsoft[hop * 3 + 0], w1 = wsoft[hop * 3 + 1], w2 = wsoft[hop * 3 + 2];
        float wiv0 = w0 * i0, wiv1 = w1 * i1, wiv2 = w2 * i2;
        float4 acc = f4_zero();
        #pragma unroll
        for (int r = 0; r < RE; r++) {
            if (r < deg) {
                int p = __shfl(myp, r, 16);
                int v = p >> 18;
                float4 x = xc[r];
                float4 uv2 = (v == 0) ? u20 : ((v == 1) ? u21 : u22);
                float d2 = red16(f4_dot(uv2, x));
                float d1 = __shfl(d1me, r, 16);
                float wiv = (v == 0) ? wiv0 : ((v == 1) ? wiv1 : wiv2);
                acc = f4_fma(d1 * d1 * d2 * wiv, x, acc);
            }
        }
        #pragma unroll
        for (int r = RE; r < 16; r++) {
            if (r < deg) {
                int p = __shfl(myp, r, 16);
                int v = p >> 18;
                float4 x = entv[(p & 0x3FFFF) * 16 + lane];
                float4 uv2 = (v == 0) ? u20 : ((v == 1) ? u21 : u22);
                float d2 = red16(f4_dot(uv2, x));
                float d1 = __shfl(d1me, r, 16);
                float wiv = (v == 0) ? wiv0 : ((v == 1) ? wiv1 : wiv2);
                acc = f4_fma(d1 * d1 * d2 * wiv, x, acc);
            }
        }
        for (int e = start + 16; e < end; e++) {
            int p = sorted[e];
            int v = p >> 18;
            float4 x = entv[(p & 0x3FFFF) * 16 + lane];
            float4 uv1 = (v == 0) ? u10 : ((v == 1) ? u11 : u12);
            float4 uv2 = (v == 0) ? u20 : ((v == 1) ? u21 : u22);
            float d1 = red16(f4_dot(uv1, x));
            float d2 = red16(f4_dot(uv2, x));
            float wiv = (v == 0) ? wiv0 : ((v == 1) ? wiv1 : wiv2);
            acc = f4_fma(d1 * d1 * d2 * wiv, x, acc);
        }

        float4 agg = f4_add(eh, acc);   // sum_v w_v*eh = eh since sum w = 1
        sq = red16(f4_dot(agg, agg));
        float nn = sqrtf(sq);
        float4 en = f4_scale(1.f / fmaxf(nn, EPSF), agg);
        if (do_store) ((float4*)ent_next)[g * 16 + lane] = en;
        float4* outv = (float4*)outE;
        float4 base = first ? eh : outv[g * 16 + lane];
        outv[g * 16 + lane] = f4_add(base, en);
    } else {
        // ================= user path =================
        int gu = (blockIdx.x - NBLK_E) * 16 + (threadIdx.x >> 4);
        int start = rp[N_ENT + gu], end = rp[N_ENT + gu + 1];
        int deg = end - start;
        int deg16 = (deg < 16) ? deg : 16;
        const float4* usrv = (const float4*)usr;
        float4 uh = usrv[gu * 16 + lane];
        float inv = 1.f / fmaxf((float)deg, 1.f);

        int myp = 0;
        if (lane < deg16) myp = sorted[start + lane];

        float4 xc[RU];
        float4 acc = f4_zero();
        // iter 0 + cache fill
        #pragma unroll
        for (int r = 0; r < RU; r++) {
            if (r < deg) {
                int p = __shfl(myp, r, 16);
                float4 x = entv[p * 16 + lane];
                xc[r] = x;
                acc = f4_add(acc, x);
            }
        }
        #pragma unroll
        for (int r = RU; r < 16; r++) {
            if (r < deg) {
                int p = __shfl(myp, r, 16);
                acc = f4_add(acc, entv[p * 16 + lane]);
            }
        }
        for (int e = start + 16; e < end; e++)
            acc = f4_add(acc, entv[sorted[e] * 16 + lane]);
        float4 u = f4_scale(inv, acc);
        float sq = red16(f4_dot(u, u));
        float4 u1 = f4_add(squash4(u, sq), uh);

        // iter 1: scale = dot(u1, x)
        acc = f4_zero();
        #pragma unroll
        for (int r = 0; r < RU; r++) {
            if (r < deg) {
                float4 x = xc[r];
                acc = f4_fma(red16(f4_dot(u1, x)), x, acc);
            }
        }
        #pragma unroll
        for (int r = RU; r < 16; r++) {
            if (r < deg) {
                int p = __shfl(myp, r, 16);
                float4 x = entv[p * 16 + lane];
                acc = f4_fma(red16(f4_dot(u1, x)), x, acc);
            }
        }
        for (int e = start + 16; e < end; e++) {
            float4 x = entv[sorted[e] * 16 + lane];
            acc = f4_fma(red16(f4_dot(u1, x)), x, acc);
        }
        u = f4_scale(inv, acc);
        sq = red16(f4_dot(u, u));
        float4 u2 = f4_add(squash4(u, sq), uh);

        // iter 2: scale = dot(u2, x)
        acc = f4_zero();
        #pragma unroll
        for (int r = 0; r < RU; r++) {
            if (r < deg) {
                float4 x = xc[r];
                acc = f4_fma(red16(f4_dot(u2, x)), x, acc);
            }
        }
        #pragma unroll
        for (int r = RU; r < 16; r++) {
            if (r < deg) {
                int p = __shfl(myp, r, 16);
                float4 x = entv[p * 16 + lane];
                acc = f4_fma(red16(f4_dot(u2, x)), x, acc);
            }
        }
        for (int e = start + 16; e < end; e++) {
            float4 x = entv[sorted[e] * 16 + lane];
            acc = f4_fma(red16(f4_dot(u2, x)), x, acc);
        }
        float4 u3 = f4_add(f4_scale(inv, acc), uh);
        sq = red16(f4_dot(u3, u3));
        float nn = sqrtf(sq);
        float4 un = f4_scale(1.f / fmaxf(nn, EPSF), u3);
        if (do_store) ((float4*)usr_next)[gu * 16 + lane] = un;
        float4* outv = (float4*)outU;
        float4 base = first ? uh : outv[gu * 16 + lane];
        outv[gu * 16 + lane] = f4_add(base, un);
    }
}

// ---------- launch ----------
extern "C" void kernel_launch(void* const* d_in, const int* in_sizes, int n_in,
                              void* d_out, int out_size, void* d_ws, size_t ws_size,
                              hipStream_t stream)
{
    const float* entity_emb = (const float*)d_in[0];
    const float* user_emb   = (const float*)d_in[1];
    const float* latent     = (const float*)d_in[2];
    const float* rel_w      = (const float*)d_in[3];
    const float* agg_w      = (const float*)d_in[4];
    const int* edge_index   = (const int*)d_in[5];
    const int* edge_type    = (const int*)d_in[6];
    const int* user_index   = (const int*)d_in[7];
    const int* item_index   = (const int*)d_in[8];
    float* out = (float*)d_out;

    char* ws = (char*)d_ws;
    size_t off = 0;
    auto alloc = [&](size_t bytes) -> void* {
        void* p = ws + off;
        off += (bytes + 255) / 256 * 256;
        return p;
    };
    float* entA  = (float*)alloc((size_t)N_ENT * DIM * 4);
    float* usrA  = (float*)alloc((size_t)N_USR * DIM * 4);
    float* wsoft = (float*)alloc(8 * 4);
    int* remap   = (int*)alloc(16 * 4);
    int* cnt     = (int*)alloc((size_t)NT * 4);
    int* rp      = (int*)alloc((size_t)(NT + 1) * 4);
    int* cur     = (int*)alloc((size_t)NT * 4);
    int* excl    = (int*)alloc((size_t)NT * 4);
    int* bsum    = (int*)alloc(1024 * 4);
    int* sorted  = (int*)alloc((size_t)NTE * 4);

    const int* head = edge_index;
    const int* tail = edge_index + NE;

    hipMemsetAsync(cnt, 0, (size_t)NT * 4, stream);

    k_remap<<<1, 32, 0, stream>>>(rel_w, latent, remap);
    k_soft<<<1, 32, 0, stream>>>(agg_w, wsoft);

    k_count_all<<<(NTE + 255) / 256, 256, 0, stream>>>(head, user_index, cnt);

    int nb = (NT + SCAN_B - 1) / SCAN_B;   // 293
    k_scan1<<<nb, SCAN_B, 0, stream>>>(cnt, excl, bsum, NT);
    k_scan2<<<1, SCAN_B, 0, stream>>>(bsum, nb);
    k_scan3<<<nb, SCAN_B, 0, stream>>>(excl, bsum, cnt, rp, cur, NT);

    k_scatter_all<<<(NTE + 255) / 256, 256, 0, stream>>>(
        head, tail, edge_type, remap, user_index, item_index, cur, sorted);

    const float* ec = entity_emb;
    const float* uc = user_emb;
    for (int hop = 0; hop < 2; hop++) {
        int do_store = (hop == 0);
        int first = (hop == 0);
        k_hop<<<NBLK_E + NBLK_U, 256, 0, stream>>>(
            ec, uc, rp, sorted, wsoft, hop, entA, usrA, do_store, first,
            out, out + (size_t)N_ENT * DIM);
        ec = entA;
        uc = usrA;
    }
}

// Round 4
// 883.099 us; speedup vs baseline: 1.4019x; 1.0083x over previous
//
#include <hip/hip_runtime.h>

#define N_ENT 200000
#define N_USR 100000
#define NT3   700000      // N_ENT*3 virt-segments + N_USR user segments
#define UKEY0 600000      // first user segment key
#define DIM 64
#define NE 1500000
#define NI_ 1000000
#define NTE 2500000       // NE + NI_
#define NREL1 10
#define NVIRT 3
#define EPSF 1e-12f
#define SCAN_B 1024
#define RE 6              // cached rows per (entity,virt) segment (Poisson ~2.5)
#define RU 12             // cached rows per user segment (Poisson ~10)

// ---------- float4 helpers ----------
__device__ __forceinline__ float4 f4_zero() { return make_float4(0.f, 0.f, 0.f, 0.f); }
__device__ __forceinline__ float4 f4_add(float4 a, float4 b) {
    return make_float4(a.x + b.x, a.y + b.y, a.z + b.z, a.w + b.w);
}
__device__ __forceinline__ float4 f4_scale(float s, float4 a) {
    return make_float4(s * a.x, s * a.y, s * a.z, s * a.w);
}
__device__ __forceinline__ float4 f4_fma(float s, float4 a, float4 b) {
    return make_float4(fmaf(s, a.x, b.x), fmaf(s, a.y, b.y), fmaf(s, a.z, b.z), fmaf(s, a.w, b.w));
}
__device__ __forceinline__ float f4_dot(float4 a, float4 b) {
    return a.x * b.x + a.y * b.y + a.z * b.z + a.w * b.w;
}
__device__ __forceinline__ float red16(float v) {
    v += __shfl_xor(v, 1, 16);
    v += __shfl_xor(v, 2, 16);
    v += __shfl_xor(v, 4, 16);
    v += __shfl_xor(v, 8, 16);
    return v;
}
__device__ __forceinline__ float4 squash4(float4 u, float sq) {
    float n = sqrtf(sq);
    float s = sq / ((sq + 1.f) * fmaxf(n, EPSF));
    return f4_scale(s, u);
}

// ---------- prep: relation->virt argmax + per-hop softmax ----------
__global__ void k_prep(const float* __restrict__ rw, const float* __restrict__ lat,
                       const float* __restrict__ aw, int* __restrict__ remap,
                       float* __restrict__ wsoft) {
    int t = threadIdx.x;
    if (t < NREL1) {
        float best = -3.4e38f; int bi = 0;
        for (int j = 0; j < NVIRT; j++) {
            float s = 0.f;
            for (int d = 0; d < DIM; d++) s += rw[t * DIM + d] * lat[j * DIM + d];
            if (s > best) { best = s; bi = j; }
        }
        remap[t] = bi;
    }
    if (t >= 32 && t < 34) {
        int h = t - 32;
        float a0 = aw[h * 3 + 0], a1 = aw[h * 3 + 1], a2 = aw[h * 3 + 2];
        float m = fmaxf(a0, fmaxf(a1, a2));
        float e0 = expf(a0 - m), e1 = expf(a1 - m), e2 = expf(a2 - m);
        float s = e0 + e1 + e2;
        wsoft[h * 3 + 0] = e0 / s; wsoft[h * 3 + 1] = e1 / s; wsoft[h * 3 + 2] = e2 / s;
    }
}

// ---------- combined CSR build, key = head*3+virt for entities, UKEY0+user for users ----------
__global__ void k_count_all(const int* __restrict__ head, const int* __restrict__ etype,
                            const int* __restrict__ remap, const int* __restrict__ uidx,
                            int* __restrict__ cnt) {
    int i = blockIdx.x * blockDim.x + threadIdx.x;
    if (i < NE) {
        int key = head[i] * 3 + remap[etype[i] - 1];
        atomicAdd(&cnt[key], 1);
    } else if (i < NTE) {
        atomicAdd(&cnt[UKEY0 + uidx[i - NE]], 1);
    }
}

__global__ void k_scan1(const int* __restrict__ in, int* __restrict__ excl,
                        int* __restrict__ bsum, int n) {
    __shared__ int s[SCAN_B];
    int tid = threadIdx.x, gid = blockIdx.x * SCAN_B + tid;
    int v = (gid < n) ? in[gid] : 0;
    s[tid] = v; __syncthreads();
    for (int off = 1; off < SCAN_B; off <<= 1) {
        int t = 0;
        if (tid >= off) t = s[tid - off];
        __syncthreads();
        s[tid] += t;
        __syncthreads();
    }
    if (gid < n) excl[gid] = s[tid] - v;
    if (tid == SCAN_B - 1) bsum[blockIdx.x] = s[tid];
}

__global__ void k_scan2(int* __restrict__ bsum, int nb) {
    __shared__ int s[SCAN_B];
    int tid = threadIdx.x;
    int v = (tid < nb) ? bsum[tid] : 0;
    s[tid] = v; __syncthreads();
    for (int off = 1; off < SCAN_B; off <<= 1) {
        int t = 0;
        if (tid >= off) t = s[tid - off];
        __syncthreads();
        s[tid] += t;
        __syncthreads();
    }
    if (tid < nb) bsum[tid] = s[tid] - v;
}

__global__ void k_scan3(const int* __restrict__ excl, const int* __restrict__ bsum,
                        const int* __restrict__ cnt, int* __restrict__ rp,
                        int* __restrict__ cur, int n) {
    int gid = blockIdx.x * SCAN_B + threadIdx.x;
    if (gid < n) {
        int v = excl[gid] + bsum[blockIdx.x];
        rp[gid] = v;
        cur[gid] = v;
        if (gid == n - 1) rp[n] = v + cnt[gid];
    }
}

__global__ void k_scatter_all(const int* __restrict__ head, const int* __restrict__ tail,
                              const int* __restrict__ etype, const int* __restrict__ remap,
                              const int* __restrict__ uidx, const int* __restrict__ iidx,
                              int* __restrict__ cur, int* __restrict__ sorted) {
    int i = blockIdx.x * blockDim.x + threadIdx.x;
    if (i < NE) {
        int key = head[i] * 3 + remap[etype[i] - 1];
        int pos = atomicAdd(&cur[key], 1);
        sorted[pos] = tail[i];
    } else if (i < NTE) {
        int j = i - NE;
        int pos = atomicAdd(&cur[UKEY0 + uidx[j]], 1);
        sorted[pos] = iidx[j];
    }
}

// ---------- merged per-hop LWS: per-virt sequential entity path + user path ----------
#define NBLK_E (N_ENT / 16)   // 12500
#define NBLK_U (N_USR / 16)   // 6250

__global__ __launch_bounds__(256, 5) void k_hop(
    const float* __restrict__ ent, const float* __restrict__ usr,
    const int* __restrict__ rp, const int* __restrict__ sorted,
    const float* __restrict__ wsoft, int hop,
    float* __restrict__ ent_next, float* __restrict__ usr_next,
    int do_store, int first,
    float* __restrict__ outE, float* __restrict__ outU)
{
    int lane = threadIdx.x & 15;
    const float4* entv = (const float4*)ent;

    if (blockIdx.x < NBLK_E) {
        // ================= entity path: 3 independent per-virt LWS =================
        int g = blockIdx.x * 16 + (threadIdx.x >> 4);
        float4 eh = entv[g * 16 + lane];
        float4 agg = f4_zero();

        for (int v = 0; v < NVIRT; v++) {
            int s = rp[g * 3 + v], e = rp[g * 3 + v + 1];
            int deg = e - s;
            float inv = 1.f / fmaxf((float)deg, 1.f);
            int myp = (lane < deg) ? sorted[s + lane] : 0;   // lane-distributed headers (first 16)

            float4 xc[RE];
            // ---- iter 0 (+ cache fill)
            float4 acc = f4_zero();
            #pragma unroll
            for (int r = 0; r < RE; r++) {
                if (r < deg) {
                    int p = __shfl(myp, r, 16);
                    float4 x = entv[p * 16 + lane];
                    xc[r] = x;
                    acc = f4_add(acc, x);
                }
            }
            for (int r = RE; r < deg; r++) {
                int p = (r < 16) ? __shfl(myp, r, 16) : sorted[s + r];
                acc = f4_add(acc, entv[p * 16 + lane]);
            }
            float4 u = f4_scale(inv, acc);
            float sq = red16(f4_dot(u, u));
            float4 u1 = f4_add(squash4(u, sq), eh);

            // ---- iter 1: d1 = u1.x ; cache d1 lane-distributed
            acc = f4_zero();
            float d1me = 0.f;
            #pragma unroll
            for (int r = 0; r < RE; r++) {
                if (r < deg) {
                    float4 x = xc[r];
                    float d1 = red16(f4_dot(u1, x));
                    if (lane == r) d1me = d1;
                    acc = f4_fma(d1, x, acc);
                }
            }
            for (int r = RE; r < deg; r++) {
                int p = (r < 16) ? __shfl(myp, r, 16) : sorted[s + r];
                float4 x = entv[p * 16 + lane];
                float d1 = red16(f4_dot(u1, x));
                if (lane == r) d1me = d1;      // only lanes 0..15, so only r<16 captured
                acc = f4_fma(d1, x, acc);
            }
            u = f4_scale(inv, acc);
            sq = red16(f4_dot(u, u));
            float4 u2 = f4_add(squash4(u, sq), eh);

            // ---- iter 2: scale = d1^2 * d2
            acc = f4_zero();
            #pragma unroll
            for (int r = 0; r < RE; r++) {
                if (r < deg) {
                    float4 x = xc[r];
                    float d2 = red16(f4_dot(u2, x));
                    float d1 = __shfl(d1me, r, 16);
                    acc = f4_fma(d1 * d1 * d2, x, acc);
                }
            }
            for (int r = RE; r < deg; r++) {
                int p = (r < 16) ? __shfl(myp, r, 16) : sorted[s + r];
                float4 x = entv[p * 16 + lane];
                float d2 = red16(f4_dot(u2, x));
                float d1 = (r < 16) ? __shfl(d1me, r, 16) : red16(f4_dot(u1, x));
                acc = f4_fma(d1 * d1 * d2, x, acc);
            }
            float w = wsoft[hop * 3 + v];
            agg = f4_fma(w * inv, acc, agg);
        }
        // Σ_v w_v*(inv_v*acc_v + eh) = agg + eh  (Σw = 1)
        agg = f4_add(agg, eh);
        float sq = red16(f4_dot(agg, agg));
        float nn = sqrtf(sq);
        float4 en = f4_scale(1.f / fmaxf(nn, EPSF), agg);
        if (do_store) ((float4*)ent_next)[g * 16 + lane] = en;
        float4* outv = (float4*)outE;
        float4 base = first ? eh : outv[g * 16 + lane];
        outv[g * 16 + lane] = f4_add(base, en);
    } else {
        // ================= user path =================
        int gu = (blockIdx.x - NBLK_E) * 16 + (threadIdx.x >> 4);
        int s = rp[UKEY0 + gu], e = rp[UKEY0 + gu + 1];
        int deg = e - s;
        const float4* usrv = (const float4*)usr;
        float4 uh = usrv[gu * 16 + lane];
        float inv = 1.f / fmaxf((float)deg, 1.f);

        int deg16 = (deg < 16) ? deg : 16;
        int myp = (lane < deg16) ? sorted[s + lane] : 0;

        float4 xc[RU];
        float4 acc = f4_zero();
        // iter 0 + cache fill
        #pragma unroll
        for (int r = 0; r < RU; r++) {
            if (r < deg) {
                int p = __shfl(myp, r, 16);
                float4 x = entv[p * 16 + lane];
                xc[r] = x;
                acc = f4_add(acc, x);
            }
        }
        for (int r = RU; r < deg; r++) {
            int p = (r < 16) ? __shfl(myp, r, 16) : sorted[s + r];
            acc = f4_add(acc, entv[p * 16 + lane]);
        }
        float4 u = f4_scale(inv, acc);
        float sq = red16(f4_dot(u, u));
        float4 u1 = f4_add(squash4(u, sq), uh);

        // iter 1: scale = dot(u1, x)
        acc = f4_zero();
        #pragma unroll
        for (int r = 0; r < RU; r++) {
            if (r < deg) {
                float4 x = xc[r];
                acc = f4_fma(red16(f4_dot(u1, x)), x, acc);
            }
        }
        for (int r = RU; r < deg; r++) {
            int p = (r < 16) ? __shfl(myp, r, 16) : sorted[s + r];
            float4 x = entv[p * 16 + lane];
            acc = f4_fma(red16(f4_dot(u1, x)), x, acc);
        }
        u = f4_scale(inv, acc);
        sq = red16(f4_dot(u, u));
        float4 u2 = f4_add(squash4(u, sq), uh);

        // iter 2: scale = dot(u2, x)
        acc = f4_zero();
        #pragma unroll
        for (int r = 0; r < RU; r++) {
            if (r < deg) {
                float4 x = xc[r];
                acc = f4_fma(red16(f4_dot(u2, x)), x, acc);
            }
        }
        for (int r = RU; r < deg; r++) {
            int p = (r < 16) ? __shfl(myp, r, 16) : sorted[s + r];
            float4 x = entv[p * 16 + lane];
            acc = f4_fma(red16(f4_dot(u2, x)), x, acc);
        }
        float4 u3 = f4_add(f4_scale(inv, acc), uh);
        sq = red16(f4_dot(u3, u3));
        float nn = sqrtf(sq);
        float4 un = f4_scale(1.f / fmaxf(nn, EPSF), u3);
        if (do_store) ((float4*)usr_next)[gu * 16 + lane] = un;
        float4* outv = (float4*)outU;
        float4 base = first ? uh : outv[gu * 16 + lane];
        outv[gu * 16 + lane] = f4_add(base, un);
    }
}

// ---------- launch ----------
extern "C" void kernel_launch(void* const* d_in, const int* in_sizes, int n_in,
                              void* d_out, int out_size, void* d_ws, size_t ws_size,
                              hipStream_t stream)
{
    const float* entity_emb = (const float*)d_in[0];
    const float* user_emb   = (const float*)d_in[1];
    const float* latent     = (const float*)d_in[2];
    const float* rel_w      = (const float*)d_in[3];
    const float* agg_w      = (const float*)d_in[4];
    const int* edge_index   = (const int*)d_in[5];
    const int* edge_type    = (const int*)d_in[6];
    const int* user_index   = (const int*)d_in[7];
    const int* item_index   = (const int*)d_in[8];
    float* out = (float*)d_out;

    char* ws = (char*)d_ws;
    size_t off = 0;
    auto alloc = [&](size_t bytes) -> void* {
        void* p = ws + off;
        off += (bytes + 255) / 256 * 256;
        return p;
    };
    float* entA  = (float*)alloc((size_t)N_ENT * DIM * 4);
    float* usrA  = (float*)alloc((size_t)N_USR * DIM * 4);
    float* wsoft = (float*)alloc(8 * 4);
    int* remap   = (int*)alloc(16 * 4);
    int* cnt     = (int*)alloc((size_t)NT3 * 4);
    int* rp      = (int*)alloc((size_t)(NT3 + 1) * 4);
    int* cur     = (int*)alloc((size_t)NT3 * 4);
    int* excl    = (int*)alloc((size_t)NT3 * 4);
    int* bsum    = (int*)alloc(1024 * 4);
    int* sorted  = (int*)alloc((size_t)NTE * 4);

    const int* head = edge_index;
    const int* tail = edge_index + NE;

    hipMemsetAsync(cnt, 0, (size_t)NT3 * 4, stream);

    k_prep<<<1, 64, 0, stream>>>(rel_w, latent, agg_w, remap, wsoft);

    k_count_all<<<(NTE + 255) / 256, 256, 0, stream>>>(head, edge_type, remap, user_index, cnt);

    int nb = (NT3 + SCAN_B - 1) / SCAN_B;   // 684 <= 1024
    k_scan1<<<nb, SCAN_B, 0, stream>>>(cnt, excl, bsum, NT3);
    k_scan2<<<1, SCAN_B, 0, stream>>>(bsum, nb);
    k_scan3<<<nb, SCAN_B, 0, stream>>>(excl, bsum, cnt, rp, cur, NT3);

    k_scatter_all<<<(NTE + 255) / 256, 256, 0, stream>>>(
        head, tail, edge_type, remap, user_index, item_index, cur, sorted);

    const float* ec = entity_emb;
    const float* uc = user_emb;
    for (int hop = 0; hop < 2; hop++) {
        int do_store = (hop == 0);
        int first = (hop == 0);
        k_hop<<<NBLK_E + NBLK_U, 256, 0, stream>>>(
            ec, uc, rp, sorted, wsoft, hop, entA, usrA, do_store, first,
            out, out + (size_t)N_ENT * DIM);
        ec = entA;
        uc = usrA;
    }
}